// Round 2
// baseline (419.326 us; speedup 1.0000x reference)
//
#include <hip/hip_runtime.h>

#define T_DIM 512
#define L_DIM 128

typedef _Float16 h2 __attribute__((ext_vector_type(2)));
typedef float f2 __attribute__((ext_vector_type(2)));

#if defined(__has_builtin)
#if __has_builtin(__builtin_amdgcn_fdot2)
#define HAS_FDOT2 1
#endif
#endif

__device__ __forceinline__ float fdot2_acc(h2 a, h2 b, float c) {
#ifdef HAS_FDOT2
    return __builtin_amdgcn_fdot2(a, b, c, false);
#else
    return c + (float)a.x * (float)b.x + (float)a.y * (float)b.y;
#endif
}

__device__ __forceinline__ unsigned int pack_u32(float a, float b) {
    // cvt_pkrtz returns a 2 x __fp16 vector (4 bytes); bit-cast it directly.
    return __builtin_bit_cast(unsigned int, __builtin_amdgcn_cvt_pkrtz(a, b));
}

__device__ __forceinline__ h2 pack_h2(float a, float b) {
    return __builtin_bit_cast(h2, __builtin_amdgcn_cvt_pkrtz(a, b));
}

// One wave (64 lanes) = one batch chain. Lane owns output labels j0=2*lane,
// j0+1. Ehat = exp(transfer)/128 lives ENTIRELY in VGPRs: 64 h2 pairs
// (along i) per column x 2 columns = 128 VGPRs. State u (128 f16 = 256 B)
// lives in LDS, double-buffered; every lane broadcast-reads all of it as
// 16 x ds_read_b128 (uniform address = conflict-free broadcast).
//
// NO s_barrier anywhere: intra-wave LDS RAW is ordered by lgkmcnt alone.
// Per step: 128 fdot2 (8 independent 16-deep chains), 1 ds_write_b32,
// lgkmcnt(0). Global feats prefetch (vmcnt) stays in flight across steps.
__global__ __launch_bounds__(64, 1) void crf_fwd_kernel(
    const float* __restrict__ feats,
    const float* __restrict__ transfer,
    const int* __restrict__ target,
    const int* __restrict__ startp,
    const int* __restrict__ stopp,
    float* __restrict__ out)
{
    __shared__ unsigned int LdsU[2][64] __attribute__((aligned(16)));

    const int lane = threadIdx.x;       // 0..63
    const int j0   = lane << 1;         // even label; lane also owns j0+1
    const int b    = blockIdx.x;
    const int start = startp[0];
    const int stop  = stopp[0];
    const float* fbase = feats + (size_t)b * T_DIM * L_DIM;
    const float LOG128 = 4.852030263919617f;
    const float SCALE  = 0.0078125f;    // 1/128 folded into Ehat

    // ---- one-time: Ehat = two full columns in regs ----
    // E0[q] = (Ehat[2q][j0],   Ehat[2q+1][j0])
    // E1[q] = (Ehat[2q][j0+1], Ehat[2q+1][j0+1])
    h2 E0[64], E1[64];
#pragma unroll
    for (int q = 0; q < 64; ++q) {
        f2 r0 = *reinterpret_cast<const f2*>(&transfer[(2 * q)     * L_DIM + j0]);
        f2 r1 = *reinterpret_cast<const f2*>(&transfer[(2 * q + 1) * L_DIM + j0]);
        E0[q] = pack_h2(__expf(r0.x) * SCALE, __expf(r1.x) * SCALE);
        E1[q] = pack_h2(__expf(r0.y) * SCALE, __expf(r1.y) * SCALE);
    }
    const float trStop0 = transfer[j0 * L_DIM + stop];
    const float trStop1 = transfer[(j0 + 1) * L_DIM + stop];

    // ---- init: u = exp(f_1 + tr[start] + f_2) (small values, no norm) ----
    {
        f2 f1v = *reinterpret_cast<const f2*>(&fbase[1 * L_DIM + j0]);
        f2 f2v = *reinterpret_cast<const f2*>(&fbase[2 * L_DIM + j0]);
        f2 tsv = *reinterpret_cast<const f2*>(&transfer[start * L_DIM + j0]);
        float v0 = f1v.x + f2v.x + tsv.x;
        float v1 = f1v.y + f2v.y + tsv.y;
        LdsU[0][lane] = pack_u32(__expf(v0), __expf(v1));
    }
    // feats prefetch pipeline, 3 iterations deep (~1200 cy > HBM latency)
    f2 fa2 = *reinterpret_cast<const f2*>(&fbase[3 * L_DIM + j0]);  // f_{t+1} at t=2
    f2 fb2 = *reinterpret_cast<const f2*>(&fbase[4 * L_DIM + j0]);
    f2 fc2 = *reinterpret_cast<const f2*>(&fbase[5 * L_DIM + j0]);
    float S = 0.f;
    asm volatile("s_waitcnt lgkmcnt(0)" ::: "memory");  // init write visible (same wave)

    int cur = 0;
    float accF0 = 0.f, accF1 = 0.f;

    for (int t = 2; t <= T_DIM - 1; ++t) {
        int tp = t + 4; if (tp > T_DIM - 1) tp = T_DIM - 1;
        f2 fnew2 = *reinterpret_cast<const f2*>(&fbase[tp * L_DIM + j0]);  // in flight (vmcnt)
        float e0 = __expf(fa2.x);
        float e1 = __expf(fa2.y);

        if ((t & 15) == 0) {            // periodic renorm, off critical path
            h2 h = __builtin_bit_cast(h2, LdsU[cur][0]);
            float u0 = (float)h.x;
            float r = 1.0f / u0;
            e0 *= r; e1 *= r;
            S += __logf(u0);
        }

        const uint4* U4 = reinterpret_cast<const uint4*>(&LdsU[cur][0]);
        float a0[4] = {0.f, 0.f, 0.f, 0.f};
        float a1[4] = {0.f, 0.f, 0.f, 0.f};
#pragma unroll
        for (int g = 0; g < 16; ++g) {
            uint4 p = U4[g];            // broadcast ds_read_b128
            const int c = g >> 2;       // static after unroll
            a0[c] = fdot2_acc(__builtin_bit_cast(h2, p.x), E0[4 * g + 0], a0[c]);
            a0[c] = fdot2_acc(__builtin_bit_cast(h2, p.y), E0[4 * g + 1], a0[c]);
            a0[c] = fdot2_acc(__builtin_bit_cast(h2, p.z), E0[4 * g + 2], a0[c]);
            a0[c] = fdot2_acc(__builtin_bit_cast(h2, p.w), E0[4 * g + 3], a0[c]);
            a1[c] = fdot2_acc(__builtin_bit_cast(h2, p.x), E1[4 * g + 0], a1[c]);
            a1[c] = fdot2_acc(__builtin_bit_cast(h2, p.y), E1[4 * g + 1], a1[c]);
            a1[c] = fdot2_acc(__builtin_bit_cast(h2, p.z), E1[4 * g + 2], a1[c]);
            a1[c] = fdot2_acc(__builtin_bit_cast(h2, p.w), E1[4 * g + 3], a1[c]);
        }
        float acc0 = (a0[0] + a0[1]) + (a0[2] + a0[3]);
        float acc1 = (a1[0] + a1[1]) + (a1[2] + a1[3]);

        if (t < T_DIM - 1) {
            LdsU[cur ^ 1][lane] = pack_u32(acc0 * e0, acc1 * e1);
            // order write -> next-iter reads within the wave; vmcnt untouched
            asm volatile("s_waitcnt lgkmcnt(0)" ::: "memory");
            cur ^= 1;
            fa2 = fb2; fb2 = fc2; fc2 = fnew2;
        } else {
            accF0 = acc0; accF1 = acc1;
        }
    }

    // 510 dots, each carrying the folded 1/128
    S += 510.0f * LOG128;

    // ---- sentence = LSE_j(log u_j + S + tr[j,stop]) — pure shuffles ----
    float x0 = __logf(accF0) + S + trStop0;
    float x1 = __logf(accF1) + S + trStop1;
    float mx = fmaxf(x0, x1);
#pragma unroll
    for (int d = 1; d < 64; d <<= 1) mx = fmaxf(mx, __shfl_xor(mx, d));
    float ex = __expf(x0 - mx) + __expf(x1 - mx);
#pragma unroll
    for (int d = 1; d < 64; d <<= 1) ex += __shfl_xor(ex, d);
    float sentence = mx + __logf(ex);

    // ---- gold score: 8 t's per lane, coalesced target loads ----
    float es = 0.f, ts = 0.f;
    const int* tgt = target + b * T_DIM;
#pragma unroll
    for (int k = 0; k < 8; ++k) {
        int t = 1 + lane + (k << 6);
        if (t < T_DIM) {
            int tg = tgt[t];
            es += fbase[t * L_DIM + tg];
            int pr = (t == 1) ? start : tgt[t - 1];
            ts += transfer[pr * L_DIM + tg];
        }
    }
#pragma unroll
    for (int d = 1; d < 64; d <<= 1) {
        es += __shfl_xor(es, d);
        ts += __shfl_xor(ts, d);
    }
    if (lane == 0) {
        float emit0 = fbase[start];     // feats[b, 0, start]
        out[b] = sentence - __expf(emit0 + es + ts);
    }
}

extern "C" void kernel_launch(void* const* d_in, const int* in_sizes, int n_in,
                              void* d_out, int out_size, void* d_ws, size_t ws_size,
                              hipStream_t stream) {
    const float* feats    = (const float*)d_in[0];
    const float* transfer = (const float*)d_in[1];
    const int*   target   = (const int*)d_in[2];
    const int*   startp   = (const int*)d_in[3];
    const int*   stopp    = (const int*)d_in[4];
    float* outp = (float*)d_out;
    int B = in_sizes[0] / (T_DIM * L_DIM);
    hipLaunchKernelGGL(crf_fwd_kernel, dim3(B), dim3(64), 0, stream,
                       feats, transfer, target, startp, stopp, outp);
}

// Round 3
// 411.346 us; speedup vs baseline: 1.0194x; 1.0194x over previous
//
#include <hip/hip_runtime.h>

#define T_DIM 512
#define L_DIM 128

typedef _Float16 h2 __attribute__((ext_vector_type(2)));
typedef float f2 __attribute__((ext_vector_type(2)));

#if defined(__has_builtin)
#if __has_builtin(__builtin_amdgcn_fdot2)
#define HAS_FDOT2 1
#endif
#endif

__device__ __forceinline__ float fdot2_acc(h2 a, h2 b, float c) {
#ifdef HAS_FDOT2
    return __builtin_amdgcn_fdot2(a, b, c, false);
#else
    return c + (float)a.x * (float)b.x + (float)a.y * (float)b.y;
#endif
}

__device__ __forceinline__ unsigned int pack_u32(float a, float b) {
    return __builtin_bit_cast(unsigned int, __builtin_amdgcn_cvt_pkrtz(a, b));
}

#define H2C(x) __builtin_bit_cast(h2, (x))

// One wave (64 lanes) = one batch chain. Lane owns output labels j0=2*lane,
// j0+1. Ehat = exp(transfer)/128 lives in VGPRs as 32 NAMED uint4 vars
// (16 groups x 2 columns; group v = i-rows 8v..8v+7). Named struct-field
// access only => SROA keeps them in registers (round-2's E0[64]/E1[64]
// arrays went to scratch: VGPR_Count=108 < the 128 needed, ~3x slowdown).
//
// State u (128 f16 = 256 B) lives in LDS, double-buffered; every lane
// broadcast-reads it as 16 x ds_read_b128 (uniform addr = conflict-free).
// NO s_barrier anywhere: intra-wave LDS RAW ordered by lgkmcnt alone.
// Global feats prefetch (vmcnt) stays in flight across steps.

#define E_GROUPS(X) X(0) X(1) X(2) X(3) X(4) X(5) X(6) X(7) \
                    X(8) X(9) X(10) X(11) X(12) X(13) X(14) X(15)

__global__ __launch_bounds__(64, 1) void crf_fwd_kernel(
    const float* __restrict__ feats,
    const float* __restrict__ transfer,
    const int* __restrict__ target,
    const int* __restrict__ startp,
    const int* __restrict__ stopp,
    float* __restrict__ out)
{
    __shared__ unsigned int LdsU[2][64] __attribute__((aligned(16)));

    const int lane = threadIdx.x;       // 0..63
    const int j0   = lane << 1;         // even label; lane also owns j0+1
    const int b    = blockIdx.x;
    const int start = startp[0];
    const int stop  = stopp[0];
    const float* fbase = feats + (size_t)b * T_DIM * L_DIM;
    const float LOG128 = 4.852030263919617f;
    const float SCALE  = 0.0078125f;    // 1/128 folded into Ehat

    // ---- Ehat: 32 named uint4 (EA* = col j0, EB* = col j0+1) ----
#define DECL_E(v) uint4 EA##v, EB##v;
    E_GROUPS(DECL_E)
#undef DECL_E

#define LD2(r) (*reinterpret_cast<const f2*>(&transfer[(r) * L_DIM + j0]))
#define LOAD_E(v) { \
    f2 r0 = LD2(8*(v)+0), r1 = LD2(8*(v)+1), r2 = LD2(8*(v)+2), r3 = LD2(8*(v)+3); \
    f2 r4 = LD2(8*(v)+4), r5 = LD2(8*(v)+5), r6 = LD2(8*(v)+6), r7 = LD2(8*(v)+7); \
    EA##v.x = pack_u32(__expf(r0.x)*SCALE, __expf(r1.x)*SCALE); \
    EA##v.y = pack_u32(__expf(r2.x)*SCALE, __expf(r3.x)*SCALE); \
    EA##v.z = pack_u32(__expf(r4.x)*SCALE, __expf(r5.x)*SCALE); \
    EA##v.w = pack_u32(__expf(r6.x)*SCALE, __expf(r7.x)*SCALE); \
    EB##v.x = pack_u32(__expf(r0.y)*SCALE, __expf(r1.y)*SCALE); \
    EB##v.y = pack_u32(__expf(r2.y)*SCALE, __expf(r3.y)*SCALE); \
    EB##v.z = pack_u32(__expf(r4.y)*SCALE, __expf(r5.y)*SCALE); \
    EB##v.w = pack_u32(__expf(r6.y)*SCALE, __expf(r7.y)*SCALE); }
    E_GROUPS(LOAD_E)
#undef LOAD_E
#undef LD2

    const float trStop0 = transfer[j0 * L_DIM + stop];
    const float trStop1 = transfer[(j0 + 1) * L_DIM + stop];

    // ---- init: u = exp(f_1 + tr[start] + f_2) (small values, no norm) ----
    {
        f2 f1v = *reinterpret_cast<const f2*>(&fbase[1 * L_DIM + j0]);
        f2 f2v = *reinterpret_cast<const f2*>(&fbase[2 * L_DIM + j0]);
        f2 tsv = *reinterpret_cast<const f2*>(&transfer[start * L_DIM + j0]);
        LdsU[0][lane] = pack_u32(__expf(f1v.x + f2v.x + tsv.x),
                                 __expf(f1v.y + f2v.y + tsv.y));
    }
    // feats prefetch pipeline, 3 iterations deep
    f2 fa2 = *reinterpret_cast<const f2*>(&fbase[3 * L_DIM + j0]);  // f_{t+1} at t=2
    f2 fb2 = *reinterpret_cast<const f2*>(&fbase[4 * L_DIM + j0]);
    f2 fc2 = *reinterpret_cast<const f2*>(&fbase[5 * L_DIM + j0]);
    float S = 0.f;
    asm volatile("s_waitcnt lgkmcnt(0)" ::: "memory");  // init write visible (same wave)

    int cur = 0;
    float accF0 = 0.f, accF1 = 0.f;

    for (int t = 2; t <= T_DIM - 1; ++t) {
        int tp = t + 4; if (tp > T_DIM - 1) tp = T_DIM - 1;
        f2 fnew2 = *reinterpret_cast<const f2*>(&fbase[tp * L_DIM + j0]);  // in flight (vmcnt)
        float e0 = __expf(fa2.x);
        float e1 = __expf(fa2.y);

        if ((t & 15) == 0) {            // periodic renorm, off critical path
            h2 h = H2C(LdsU[cur][0]);
            float u0 = (float)h.x;
            float r = 1.0f / u0;
            e0 *= r; e1 *= r;
            S += __logf(u0);
        }

        const uint4* U4p = reinterpret_cast<const uint4*>(&LdsU[cur][0]);
        float s0 = 0.f, s1 = 0.f, s2 = 0.f, s3 = 0.f;   // col j0
        float q0 = 0.f, q1 = 0.f, q2 = 0.f, q3 = 0.f;   // col j0+1

#define DOT_G(v, AC, BC) { \
        uint4 p = U4p[v]; \
        AC = fdot2_acc(H2C(p.x), H2C(EA##v.x), AC); \
        AC = fdot2_acc(H2C(p.y), H2C(EA##v.y), AC); \
        AC = fdot2_acc(H2C(p.z), H2C(EA##v.z), AC); \
        AC = fdot2_acc(H2C(p.w), H2C(EA##v.w), AC); \
        BC = fdot2_acc(H2C(p.x), H2C(EB##v.x), BC); \
        BC = fdot2_acc(H2C(p.y), H2C(EB##v.y), BC); \
        BC = fdot2_acc(H2C(p.z), H2C(EB##v.z), BC); \
        BC = fdot2_acc(H2C(p.w), H2C(EB##v.w), BC); }

        DOT_G(0,  s0, q0) DOT_G(1,  s1, q1) DOT_G(2,  s2, q2) DOT_G(3,  s3, q3)
        DOT_G(4,  s0, q0) DOT_G(5,  s1, q1) DOT_G(6,  s2, q2) DOT_G(7,  s3, q3)
        DOT_G(8,  s0, q0) DOT_G(9,  s1, q1) DOT_G(10, s2, q2) DOT_G(11, s3, q3)
        DOT_G(12, s0, q0) DOT_G(13, s1, q1) DOT_G(14, s2, q2) DOT_G(15, s3, q3)
#undef DOT_G

        float acc0 = (s0 + s1) + (s2 + s3);
        float acc1 = (q0 + q1) + (q2 + q3);

        if (t < T_DIM - 1) {
            LdsU[cur ^ 1][lane] = pack_u32(acc0 * e0, acc1 * e1);
            // order write -> next-iter reads within the wave; vmcnt untouched
            asm volatile("s_waitcnt lgkmcnt(0)" ::: "memory");
            cur ^= 1;
            fa2 = fb2; fb2 = fc2; fc2 = fnew2;
        } else {
            accF0 = acc0; accF1 = acc1;
        }
    }

    // 510 dots, each carrying the folded 1/128
    S += 510.0f * LOG128;

    // ---- sentence = LSE_j(log u_j + S + tr[j,stop]) — pure shuffles ----
    float x0 = __logf(accF0) + S + trStop0;
    float x1 = __logf(accF1) + S + trStop1;
    float mx = fmaxf(x0, x1);
#pragma unroll
    for (int d = 1; d < 64; d <<= 1) mx = fmaxf(mx, __shfl_xor(mx, d));
    float ex = __expf(x0 - mx) + __expf(x1 - mx);
#pragma unroll
    for (int d = 1; d < 64; d <<= 1) ex += __shfl_xor(ex, d);
    float sentence = mx + __logf(ex);

    // ---- gold score: 8 t's per lane, coalesced target loads ----
    float es = 0.f, ts = 0.f;
    const int* tgt = target + b * T_DIM;
#pragma unroll
    for (int k = 0; k < 8; ++k) {
        int t = 1 + lane + (k << 6);
        if (t < T_DIM) {
            int tg = tgt[t];
            es += fbase[t * L_DIM + tg];
            int pr = (t == 1) ? start : tgt[t - 1];
            ts += transfer[pr * L_DIM + tg];
        }
    }
#pragma unroll
    for (int d = 1; d < 64; d <<= 1) {
        es += __shfl_xor(es, d);
        ts += __shfl_xor(ts, d);
    }
    if (lane == 0) {
        float emit0 = fbase[start];     // feats[b, 0, start]
        out[b] = sentence - __expf(emit0 + es + ts);
    }
}

extern "C" void kernel_launch(void* const* d_in, const int* in_sizes, int n_in,
                              void* d_out, int out_size, void* d_ws, size_t ws_size,
                              hipStream_t stream) {
    const float* feats    = (const float*)d_in[0];
    const float* transfer = (const float*)d_in[1];
    const int*   target   = (const int*)d_in[2];
    const int*   startp   = (const int*)d_in[3];
    const int*   stopp    = (const int*)d_in[4];
    float* outp = (float*)d_out;
    int B = in_sizes[0] / (T_DIM * L_DIM);
    hipLaunchKernelGGL(crf_fwd_kernel, dim3(B), dim3(64), 0, stream,
                       feats, transfer, target, startp, stopp, outp);
}